// Round 6
// baseline (372.907 us; speedup 1.0000x reference)
//
#include <hip/hip_runtime.h>
#include <math.h>

#define NV 32768
#define CD 128
#define NCLS 10
#define KSEL 500
#define BNEPS 1e-5f
#define NK (NCLS * NV)            // 327680 keys per batch
#define H1CUT 0x3E00              // score >= 0.125 ; bins (s>>16)-H1CUT in [0,384)
#define H1BINS 384
#define CANDCAP 2048
#define ABLKROWS 64
#define ABLKPERB (NV / ABLKROWS)  // 512 stageA blocks per batch
#define BCHUNKS 8
#define CHUNKSZ (NK / BCHUNKS)    // 40960

// ---------------------------------------------------------------------------
// Stage A: hm head over all voxels. 64 rows x 128 cols per block (256 thr).
// NEW decomposition: wave w owns cols [32w,32w+32), lane owns one row.
// -> W1 accesses are wave-uniform => scalar s_load into SGPRs (no VALU, no
//    LDS, no per-lane vmcnt), FMA = ~90% of VALU issue.
// -> feats transposed in LDS fsT[k][row] stride 65: inner read is one
//    conflict-free ds_read_b32 per k per wave.
// Per-element fmaf k-order identical to R1-R5 -> scores bit-identical.
// Epilogue: BN+ReLU (same formulas), act->LDS overlay, GEMM2 (same c-order),
// sigmoid, score bits, hist1 partials; zeroes hist2 slice + cnt.
// ---------------------------------------------------------------------------
__global__ __launch_bounds__(256, 4) void stageA_kernel(
    const float* __restrict__ feats,
    const float* __restrict__ W1,
    const float* __restrict__ b1,
    const float* __restrict__ bng,
    const float* __restrict__ bnb,
    const float* __restrict__ bnm,
    const float* __restrict__ bnv,
    const float* __restrict__ W2hm,
    const float* __restrict__ b2hm,
    unsigned int* __restrict__ scoreb,
    unsigned int* __restrict__ hist1p,
    unsigned int* __restrict__ hist2,
    unsigned int* __restrict__ cnt)
{
    __shared__ __align__(16) float fsT[CD * 65];   // [k][row], 33280 B; act overlay
    __shared__ float w2s[CD * NCLS];               // 5120 B
    __shared__ float b2s[16];
    __shared__ unsigned int lhist[H1BINS];         // 1536 B  (total 40000 B)

    const int tid = threadIdx.x;
    const int gbase = blockIdx.x * ABLKROWS;

    // zero fallback scratch + cnt
    if (tid < 128) hist2[blockIdx.x * 128 + tid] = 0u;
    if (blockIdx.x == 0 && tid < 8) cnt[tid] = 0u;
    for (int i = tid; i < H1BINS; i += 256) lhist[i] = 0u;
    for (int i = tid; i < CD * NCLS; i += 256) w2s[i] = W2hm[i];
    if (tid < NCLS) b2s[tid] = b2hm[tid];

    // stage feats tile TRANSPOSED: fsT[k*65 + r] = feats[gbase+r][k]
    for (int t = tid; t < ABLKROWS * 32; t += 256) {
        const int r = t >> 5;
        const int g = t & 31;                      // k-group
        const float4 v = *(const float4*)(feats + (((size_t)(gbase + r)) << 7) + (g << 2));
        const int k0 = g << 2;
        fsT[(k0 + 0) * 65 + r] = v.x;
        fsT[(k0 + 1) * 65 + r] = v.y;
        fsT[(k0 + 2) * 65 + r] = v.z;
        fsT[(k0 + 3) * 65 + r] = v.w;
    }
    __syncthreads();

    const int lane = tid & 63;                     // row within tile
    const int c0u = __builtin_amdgcn_readfirstlane((tid >> 6) << 5); // wave-uniform col base
    const float* __restrict__ Wu = W1 + c0u;       // scalar base -> s_load path

    float acc[32];
    #pragma unroll
    for (int c = 0; c < 32; ++c) acc[c] = 0.f;

    #pragma unroll 4
    for (int k = 0; k < 128; ++k) {
        const float f = fsT[k * 65 + lane];        // conflict-free b32 broadcast-ish
        const float* __restrict__ wr = Wu + (k << 7);
        #pragma unroll
        for (int c = 0; c < 32; ++c)
            acc[c] = fmaf(f, wr[c], acc[c]);       // v_fmac with SGPR operand
    }

    // BN (eval) + ReLU — identical formulas/order to rounds 1-5
    #pragma unroll
    for (int c = 0; c < 32; ++c) {
        const int cc = c0u + c;
        const float inv = bng[cc] / sqrtf(bnv[cc] + BNEPS);
        const float h = (acc[c] + b1[cc] - bnm[cc]) * inv + bnb[cc];
        acc[c] = fmaxf(h, 0.f);
    }

    __syncthreads();                               // fsT reads done before overlay
    // act overlay: act[r][c] stride 129 (scalar writes, 2-way = free)
    float* const act = fsT;                        // 64*129 = 8256 <= 8320
    #pragma unroll
    for (int c = 0; c < 32; ++c)
        act[lane * 129 + c0u + c] = acc[c];
    __syncthreads();

    // GEMM2: logits[r][o] = sum_c act[r][c] * W2[c][o]; sequential c order.
    const int r = tid & 63;
    const int ogrp = tid >> 6;  // wave-uniform
    float lg[3] = {0.f, 0.f, 0.f};
    for (int c = 0; c < 128; ++c) {
        const float a = act[r * 129 + c];
        #pragma unroll
        for (int i = 0; i < 3; ++i) {
            const int o = ogrp + 4 * i;
            if (o < NCLS) lg[i] = fmaf(a, w2s[c * NCLS + o], lg[i]);
        }
    }
    const int n = gbase + r;
    const int b = n >> 15;          // NV = 2^15
    const int v = n & (NV - 1);
    unsigned int* sb = scoreb + (size_t)b * NK;
    #pragma unroll
    for (int i = 0; i < 3; ++i) {
        const int o = ogrp + 4 * i;
        if (o < NCLS) {
            const float x = lg[i] + b2s[o];
            const float s = 1.f / (1.f + expf(-x));
            const unsigned int u = __float_as_uint(s);
            sb[o * NV + v] = u;
            const int rel = (int)(u >> 16) - H1CUT;
            if (rel >= 0) atomicAdd(&lhist[rel], 1u); // max rel = 383 (s < 1.0)
        }
    }
    __syncthreads();
    for (int i = tid; i < H1BINS; i += 256)
        hist1p[(size_t)blockIdx.x * H1BINS + i] = lhist[i];
}

// ---------------------------------------------------------------------------
// B5: fused t1-compute + wide filter. grid (BCHUNKS, B), 384 threads.
// ---------------------------------------------------------------------------
__global__ __launch_bounds__(384) void stageB5_kernel(
    const unsigned int* __restrict__ scoreb,
    const unsigned int* __restrict__ hist1p,
    unsigned int* __restrict__ cnt, unsigned long long* __restrict__ cand)
{
    __shared__ unsigned int histS[H1BINS];
    __shared__ unsigned int s_t1;
    const int b = blockIdx.y;
    const int tid = threadIdx.x;

    {   // sum this batch's partial hists (coalesced across tid per j)
        unsigned int sum = 0;
        const unsigned int* hp = hist1p + (size_t)b * ABLKPERB * H1BINS + tid;
        #pragma unroll 8
        for (int j = 0; j < ABLKPERB; ++j) sum += hp[(size_t)j * H1BINS];
        histS[tid] = sum;
    }
    __syncthreads();
    if (tid == 0) {
        int above = 0;
        int c = H1BINS - 1;
        for (; c > 0; --c) {
            if (above + (int)histS[c] >= KSEL) break;
            above += (int)histS[c];
        }
        s_t1 = (unsigned int)(c + H1CUT);
    }
    __syncthreads();
    const unsigned int t1 = s_t1;

    const int base = blockIdx.x * CHUNKSZ;
    const unsigned int* sb = scoreb + (size_t)b * NK + base;
    for (int i = tid; i < CHUNKSZ; i += 384) {
        const unsigned int s = sb[i];
        if ((s >> 16) >= t1) {
            const unsigned int p = atomicAdd(&cnt[b], 1u);
            if (p < CANDCAP)
                cand[(size_t)b * CANDCAP + p] =
                    ((unsigned long long)s << 32) |
                    (unsigned long long)(0xFFFFFFFFu - (unsigned int)(base + i));
        }
    }
}

// ---------------------------------------------------------------------------
// B6: per batch exact rank-by-count selection (keys unique -> ranks unique).
// rank_i = #{j: key_j > key_i}; emit rank < KSEL. O(cnt^2) broadcast compares.
// Exact hist2 fallback if candidate list overflowed (statistically never).
// ---------------------------------------------------------------------------
__global__ __launch_bounds__(1024) void stageB6_kernel(
    const unsigned int* __restrict__ scoreb,
    const unsigned int* __restrict__ hist1p,
    const unsigned int* __restrict__ cntg,
    const unsigned long long* __restrict__ candg,
    unsigned int* __restrict__ hist2,
    float* __restrict__ sel_score, int* __restrict__ sel_cls, int* __restrict__ sel_vox)
{
    __shared__ unsigned long long candL[CANDCAP];
    __shared__ unsigned int csum[1024];
    __shared__ unsigned int histS[H1BINS];
    __shared__ int s_cnt;
    __shared__ unsigned int s_T;
    const int b = blockIdx.x;
    const int tid = threadIdx.x;
    const unsigned int* sb = scoreb + (size_t)b * NK;
    int cnt = (int)cntg[b];

    if (cnt <= CANDCAP) {
        for (int i = tid; i < cnt; i += 1024)
            candL[i] = candg[(size_t)b * CANDCAP + i];
        __syncthreads();
    } else {
        // fallback: recompute t1/g1, refine exact 32-bit threshold via hist2
        if (tid < H1BINS) {
            unsigned int sum = 0;
            const unsigned int* hp = hist1p + (size_t)b * ABLKPERB * H1BINS + tid;
            for (int j = 0; j < ABLKPERB; ++j) sum += hp[(size_t)j * H1BINS];
            histS[tid] = sum;
        }
        __syncthreads();
        if (tid == 0) {
            int above = 0;
            int c = H1BINS - 1;
            for (; c > 0; --c) {
                if (above + (int)histS[c] >= KSEL) break;
                above += (int)histS[c];
            }
            s_T = (unsigned int)(c + H1CUT);   // temp: t1
            s_cnt = above;                      // temp: g1
        }
        __syncthreads();
        const unsigned int t1 = s_T;
        const unsigned int g1 = (unsigned int)s_cnt;
        __syncthreads();
        for (int i = tid; i < NK; i += 1024) {
            const unsigned int s = sb[i];
            if ((s >> 16) == t1) atomicAdd(&hist2[(size_t)b * 65536 + (s & 0xFFFFu)], 1u);
        }
        __threadfence();
        __syncthreads();
        {
            const uint4* h4 = (const uint4*)(hist2 + (size_t)b * 65536 + tid * 64);
            unsigned int sum = 0;
            #pragma unroll
            for (int i = 0; i < 16; ++i) { const uint4 v = h4[i]; sum += v.x + v.y + v.z + v.w; }
            csum[tid] = sum;
        }
        __syncthreads();
        if (tid == 0) {
            const int need = KSEL - (int)g1;
            int above = 0;
            int c = 1023;
            for (; c > 0; --c) {
                if (above + (int)csum[c] >= need) break;
                above += (int)csum[c];
            }
            const unsigned int* h2 = hist2 + (size_t)b * 65536 + c * 64;
            const int need2 = need - above;
            int above2 = 0;
            int j = 63;
            for (; j > 0; --j) {
                if (above2 + (int)h2[j] >= need2) break;
                above2 += (int)h2[j];
            }
            s_T = (t1 << 16) | (unsigned int)(c * 64 + j);
            s_cnt = 0;
        }
        __syncthreads();
        const unsigned int T = s_T;
        for (int i = tid; i < NK; i += 1024) {
            const unsigned int s = sb[i];
            if (s >= T) {
                const int p = atomicAdd(&s_cnt, 1);
                if (p < CANDCAP)
                    candL[p] = ((unsigned long long)s << 32) |
                               (unsigned long long)(0xFFFFFFFFu - (unsigned int)i);
            }
        }
        __syncthreads();
        cnt = min(s_cnt, CANDCAP);
        __syncthreads();
    }

    // exact selection by rank (order-independent, deterministic)
    for (int i = tid; i < cnt; i += 1024) {
        const unsigned long long key = candL[i];
        int rank = 0;
        for (int j = 0; j < cnt; ++j)
            rank += (candL[j] > key) ? 1 : 0;     // LDS broadcast reads
        if (rank < KSEL) {
            const unsigned int s32 = (unsigned int)(key >> 32);
            const unsigned int fl = 0xFFFFFFFFu - (unsigned int)(key & 0xFFFFFFFFull);
            const int idx = b * KSEL + rank;
            sel_score[idx] = __uint_as_float(s32);
            sel_cls[idx] = (int)(fl >> 15);
            sel_vox[idx] = (int)(fl & (NV - 1));
        }
    }
}

// ---------------------------------------------------------------------------
// Stage C: heads 1..5 for selected voxels. grid = (total/8, 5); 128 thr.
// ---------------------------------------------------------------------------
__global__ __launch_bounds__(128) void stageC_kernel(
    const float* __restrict__ feats,
    const int* __restrict__ sel_vox,
    const float* __restrict__ W1,
    const float* __restrict__ b1,
    const float* __restrict__ bng,
    const float* __restrict__ bnb,
    const float* __restrict__ bnm,
    const float* __restrict__ bnv,
    const float* __restrict__ W2c, const float* __restrict__ b2c,
    const float* __restrict__ W2z, const float* __restrict__ b2z,
    const float* __restrict__ W2d, const float* __restrict__ b2d,
    const float* __restrict__ W2r, const float* __restrict__ b2r,
    const float* __restrict__ W2v, const float* __restrict__ b2v,
    float* __restrict__ dec)
{
    __shared__ float fs[8][128];
    __shared__ float as_[8][128];
    __shared__ int vsel[8];
    const int tid = threadIdx.x;
    const int head = blockIdx.y + 1;
    const int s0 = blockIdx.x * 8;

    if (tid < 8) {
        const int s = s0 + tid;
        vsel[tid] = (s / KSEL) * NV + sel_vox[s];
    }
    __syncthreads();
    for (int t = tid; t < 8 * 128; t += 128) {
        const int j = t >> 7;
        const int c = t & 127;
        fs[j][c] = feats[((size_t)vsel[j] << 7) + c];
    }
    __syncthreads();

    const int c = tid;
    float acc[8];
    #pragma unroll
    for (int j = 0; j < 8; ++j) acc[j] = 0.f;
    const float* Wh = W1 + head * (CD * CD);
    #pragma unroll 4
    for (int k = 0; k < 128; ++k) {
        const float w = Wh[(k << 7) + c];
        #pragma unroll
        for (int j = 0; j < 8; ++j) acc[j] = fmaf(fs[j][k], w, acc[j]);
    }
    const int hc = head * CD + c;
    const float inv = bng[hc] / sqrtf(bnv[hc] + BNEPS);
    const float mu = bnm[hc], be = bnb[hc], bb = b1[hc];
    #pragma unroll
    for (int j = 0; j < 8; ++j) {
        const float h = (acc[j] + bb - mu) * inv + be;
        as_[j][c] = fmaxf(h, 0.f);
    }
    __syncthreads();

    const float* w2; const float* bb2; int oc, off; bool ex = false;
    if (head == 1)      { w2 = W2c; bb2 = b2c; oc = 2; off = 0; }
    else if (head == 2) { w2 = W2z; bb2 = b2z; oc = 1; off = 2; }
    else if (head == 3) { w2 = W2d; bb2 = b2d; oc = 3; off = 3; ex = true; }
    else if (head == 4) { w2 = W2r; bb2 = b2r; oc = 2; off = 6; }
    else                { w2 = W2v; bb2 = b2v; oc = 2; off = 8; }

    for (int t = tid; t < 8 * oc; t += 128) {
        const int j = t / oc;
        const int o = t % oc;
        float a = 0.f;
        for (int cc = 0; cc < 128; ++cc) a = fmaf(as_[j][cc], w2[cc * oc + o], a);
        a += bb2[o];
        if (ex) a = expf(a);
        dec[(size_t)(s0 + j) * 10 + off + o] = a;
    }
}

// ---------------------------------------------------------------------------
// Stage D: decode boxes + mask, write outputs.
// ---------------------------------------------------------------------------
__global__ void stageD_kernel(
    const int* __restrict__ voxel_xy,
    const float* __restrict__ sel_score,
    const int* __restrict__ sel_cls,
    const int* __restrict__ sel_vox,
    const float* __restrict__ dec,
    float* __restrict__ out,
    int total)
{
    const int s = blockIdx.x * blockDim.x + threadIdx.x;
    if (s >= total) return;
    const int b = s / KSEL;
    const float score = sel_score[s];
    const int cls = sel_cls[s];
    const int v = sel_vox[s];
    const int n = b * NV + v;
    const float xi = (float)voxel_xy[2 * n];
    const float yi = (float)voxel_xy[2 * n + 1];
    const float* dd = dec + (size_t)s * 10;
    const float cx = dd[0], cy = dd[1], cz = dd[2];
    const float d0 = dd[3], d1 = dd[4], d2 = dd[5];
    const float rc = dd[6], rs = dd[7], ve0 = dd[8], ve1 = dd[9];
    const float SV = 0.075f * 8.0f;
    const float xs = (xi + cx) * SV + (-54.0f);
    const float ys = (yi + cy) * SV + (-54.0f);
    const float ang = atan2f(rs, rc);
    const bool mk = (xs >= -61.2f) && (ys >= -61.2f) && (cz >= -10.0f) &&
                    (xs <= 61.2f) && (ys <= 61.2f) && (cz <= 10.0f) &&
                    (score > 0.1f);
    const float m = mk ? 1.f : 0.f;
    float* bx = out + (size_t)s * 10;
    bx[0] = xs * m; bx[1] = ys * m; bx[2] = cz * m;
    bx[3] = d0 * m; bx[4] = d1 * m; bx[5] = d2 * m;
    bx[6] = ang * m; bx[7] = ve0 * m; bx[8] = ve1 * m; bx[9] = score * m;
    out[(size_t)total * 10 + s] = mk ? (float)(cls + 1) : 0.f;
    out[(size_t)total * 11 + s] = (float)n;
    out[(size_t)total * 12 + s] = m;
}

extern "C" void kernel_launch(void* const* d_in, const int* in_sizes, int n_in,
                              void* d_out, int out_size, void* d_ws, size_t ws_size,
                              hipStream_t stream) {
    const float* feats   = (const float*)d_in[0];
    const int*   voxelxy = (const int*)d_in[1];
    const float* W1   = (const float*)d_in[2];
    const float* b1   = (const float*)d_in[3];
    const float* bng  = (const float*)d_in[4];
    const float* bnb  = (const float*)d_in[5];
    const float* bnm  = (const float*)d_in[6];
    const float* bnv  = (const float*)d_in[7];
    const float* W2hm = (const float*)d_in[8];
    const float* b2hm = (const float*)d_in[9];
    const float* W2c  = (const float*)d_in[10];
    const float* b2c  = (const float*)d_in[11];
    const float* W2z  = (const float*)d_in[12];
    const float* b2z  = (const float*)d_in[13];
    const float* W2d  = (const float*)d_in[14];
    const float* b2d  = (const float*)d_in[15];
    const float* W2r  = (const float*)d_in[16];
    const float* b2r  = (const float*)d_in[17];
    const float* W2v  = (const float*)d_in[18];
    const float* b2v  = (const float*)d_in[19];

    const int B = in_sizes[0] / (NV * CD);
    const int N = B * NV;
    const int total = B * KSEL;
    const int nblkA = N / ABLKROWS;

    // workspace layout (8-byte aligned chunks)
    char* ws = (char*)d_ws;
    unsigned int* scoreb = (unsigned int*)ws;   ws += (size_t)B * NK * 4;
    unsigned int* hist1p = (unsigned int*)ws;   ws += (size_t)nblkA * H1BINS * 4;
    unsigned int* hist2  = (unsigned int*)ws;   ws += (size_t)B * 65536 * 4;
    unsigned long long* cand = (unsigned long long*)ws; ws += (size_t)B * CANDCAP * 8;
    unsigned int* cnt    = (unsigned int*)ws;   ws += 8 * 4;
    float* sel_score = (float*)ws;              ws += (size_t)total * 4;
    int*   sel_cls   = (int*)ws;                ws += (size_t)total * 4;
    int*   sel_vox   = (int*)ws;                ws += (size_t)total * 4;
    float* dec       = (float*)ws;              ws += (size_t)total * 10 * 4;

    stageA_kernel<<<dim3(nblkA), dim3(256), 0, stream>>>(
        feats, W1, b1, bng, bnb, bnm, bnv, W2hm, b2hm, scoreb, hist1p, hist2, cnt);

    stageB5_kernel<<<dim3(BCHUNKS, B), dim3(384), 0, stream>>>(
        scoreb, hist1p, cnt, cand);
    stageB6_kernel<<<dim3(B), dim3(1024), 0, stream>>>(
        scoreb, hist1p, cnt, cand, hist2, sel_score, sel_cls, sel_vox);

    stageC_kernel<<<dim3(total / 8, 5), dim3(128), 0, stream>>>(
        feats, sel_vox, W1, b1, bng, bnb, bnm, bnv,
        W2c, b2c, W2z, b2z, W2d, b2d, W2r, b2r, W2v, b2v, dec);
    stageD_kernel<<<dim3((total + 255) / 256), dim3(256), 0, stream>>>(
        voxelxy, sel_score, sel_cls, sel_vox, dec, (float*)d_out, total);
}

// Round 7
// 360.302 us; speedup vs baseline: 1.0350x; 1.0350x over previous
//
#include <hip/hip_runtime.h>
#include <math.h>

#define NV 32768
#define CD 128
#define NCLS 10
#define KSEL 500
#define BNEPS 1e-5f
#define NK (NCLS * NV)            // 327680 keys per batch
#define H1CUT 0x3E00              // score >= 0.125 ; bins (s>>16)-H1CUT in [0,384)
#define H1BINS 384
#define CANDCAP 2048
#define ABLKROWS 64
#define ABLKPERB (NV / ABLKROWS)  // 512 stageA blocks per batch
#define BCHUNKS 8
#define CHUNKSZ (NK / BCHUNKS)    // 40960

// ---- W prefetch / compute macros: named float4 regs only (no arrays/fns) ----
#define LOADW(Wp, kc) do {                                                   \
    const float* _p = W1 + ((kc) << 9) + c0;                                 \
    Wp##0 = *(const float4*)(_p +   0); Wp##1 = *(const float4*)(_p +   4);  \
    Wp##2 = *(const float4*)(_p + 128); Wp##3 = *(const float4*)(_p + 132);  \
    Wp##4 = *(const float4*)(_p + 256); Wp##5 = *(const float4*)(_p + 260);  \
    Wp##6 = *(const float4*)(_p + 384); Wp##7 = *(const float4*)(_p + 388);  \
} while (0)

#define FMAK(a0, a1, a2, a3, wa, wb) do {                                    \
    acc[0][0]=fmaf(a0,wa.x,acc[0][0]); acc[0][1]=fmaf(a0,wa.y,acc[0][1]);    \
    acc[0][2]=fmaf(a0,wa.z,acc[0][2]); acc[0][3]=fmaf(a0,wa.w,acc[0][3]);    \
    acc[0][4]=fmaf(a0,wb.x,acc[0][4]); acc[0][5]=fmaf(a0,wb.y,acc[0][5]);    \
    acc[0][6]=fmaf(a0,wb.z,acc[0][6]); acc[0][7]=fmaf(a0,wb.w,acc[0][7]);    \
    acc[1][0]=fmaf(a1,wa.x,acc[1][0]); acc[1][1]=fmaf(a1,wa.y,acc[1][1]);    \
    acc[1][2]=fmaf(a1,wa.z,acc[1][2]); acc[1][3]=fmaf(a1,wa.w,acc[1][3]);    \
    acc[1][4]=fmaf(a1,wb.x,acc[1][4]); acc[1][5]=fmaf(a1,wb.y,acc[1][5]);    \
    acc[1][6]=fmaf(a1,wb.z,acc[1][6]); acc[1][7]=fmaf(a1,wb.w,acc[1][7]);    \
    acc[2][0]=fmaf(a2,wa.x,acc[2][0]); acc[2][1]=fmaf(a2,wa.y,acc[2][1]);    \
    acc[2][2]=fmaf(a2,wa.z,acc[2][2]); acc[2][3]=fmaf(a2,wa.w,acc[2][3]);    \
    acc[2][4]=fmaf(a2,wb.x,acc[2][4]); acc[2][5]=fmaf(a2,wb.y,acc[2][5]);    \
    acc[2][6]=fmaf(a2,wb.z,acc[2][6]); acc[2][7]=fmaf(a2,wb.w,acc[2][7]);    \
    acc[3][0]=fmaf(a3,wa.x,acc[3][0]); acc[3][1]=fmaf(a3,wa.y,acc[3][1]);    \
    acc[3][2]=fmaf(a3,wa.z,acc[3][2]); acc[3][3]=fmaf(a3,wa.w,acc[3][3]);    \
    acc[3][4]=fmaf(a3,wb.x,acc[3][4]); acc[3][5]=fmaf(a3,wb.y,acc[3][5]);    \
    acc[3][6]=fmaf(a3,wb.z,acc[3][6]); acc[3][7]=fmaf(a3,wb.w,acc[3][7]);    \
} while (0)

#define COMPUTE(Wp, kc) do {                                                 \
    const float4 f0 = fsmv[(r0+0)*32 + ((kc) ^ ((r0+0)&31))];                \
    const float4 f1 = fsmv[(r0+1)*32 + ((kc) ^ ((r0+1)&31))];                \
    const float4 f2 = fsmv[(r0+2)*32 + ((kc) ^ ((r0+2)&31))];                \
    const float4 f3 = fsmv[(r0+3)*32 + ((kc) ^ ((r0+3)&31))];                \
    FMAK(f0.x, f1.x, f2.x, f3.x, Wp##0, Wp##1);                              \
    FMAK(f0.y, f1.y, f2.y, f3.y, Wp##2, Wp##3);                              \
    FMAK(f0.z, f1.z, f2.z, f3.z, Wp##4, Wp##5);                              \
    FMAK(f0.w, f1.w, f2.w, f3.w, Wp##6, Wp##7);                              \
} while (0)

// ---------------------------------------------------------------------------
// Stage A: hm head over all voxels. 64 rows x 128 cols per block (256 thr),
// 4x8 per-thread micro-tile (R2 structure), W1 software-pipelined one full
// 4-k group ahead in NAMED float4 registers (ping-pong, no arrays, no guarded
// loads) to hide the ~300cy L2 latency that capped R2 at 38% VALUBusy.
// Per-accumulator k-order identical to all rounds -> scores bit-identical.
// Epilogue identical to R2/R5: BN+ReLU, act@129, GEMM2, sigmoid, score bits,
// hist1 partials; zeroes hist2 fallback slice + cnt.
// ---------------------------------------------------------------------------
__global__ __launch_bounds__(256, 4) void stageA_kernel(
    const float* __restrict__ feats,
    const float* __restrict__ W1,
    const float* __restrict__ b1,
    const float* __restrict__ bng,
    const float* __restrict__ bnb,
    const float* __restrict__ bnm,
    const float* __restrict__ bnv,
    const float* __restrict__ W2hm,
    const float* __restrict__ b2hm,
    unsigned int* __restrict__ scoreb,
    unsigned int* __restrict__ hist1p,
    unsigned int* __restrict__ hist2,
    unsigned int* __restrict__ cnt)
{
    __shared__ __align__(16) float smem[64 * 129]; // feats (f4-swizzled) / act
    __shared__ float w2s[CD * NCLS];
    __shared__ float b2s[16];
    __shared__ unsigned int lhist[H1BINS];
    float4* const fsmv = (float4*)smem;

    const int tid = threadIdx.x;
    const int gbase = blockIdx.x * ABLKROWS;

    if (tid < 128) hist2[blockIdx.x * 128 + tid] = 0u;
    if (blockIdx.x == 0 && tid < 8) cnt[tid] = 0u;
    for (int i = tid; i < H1BINS; i += 256) lhist[i] = 0u;
    for (int i = tid; i < CD * NCLS; i += 256) w2s[i] = W2hm[i];
    if (tid < NCLS) b2s[tid] = b2hm[tid];

    // feats tile -> LDS, swizzled: (r, group g) at fsmv[r*32 + (g^(r&31))]
    for (int t = tid; t < ABLKROWS * 32; t += 256) {
        const int r = t >> 5;
        const int g = t & 31;
        const float4 v = *(const float4*)(feats + (((size_t)(gbase + r)) << 7) + (g << 2));
        fsmv[r * 32 + (g ^ (r & 31))] = v;
    }
    __syncthreads();

    const int c0 = (tid & 15) << 3;   // 8 output cols
    const int r0 = (tid >> 4) << 2;   // 4 rows

    float acc[4][8];
    #pragma unroll
    for (int i = 0; i < 4; ++i)
        #pragma unroll
        for (int j = 0; j < 8; ++j) acc[i][j] = 0.f;

    // software pipeline: W for kc+1 always in flight while kc computes
    float4 w0, w1, w2, w3, w4, w5, w6, w7;
    float4 x0, x1, x2, x3, x4, x5, x6, x7;
    LOADW(w, 0);
    #pragma unroll 1
    for (int kc = 0; kc < 30; kc += 2) {
        LOADW(x, kc + 1);
        COMPUTE(w, kc);
        LOADW(w, kc + 2);
        COMPUTE(x, kc + 1);
    }
    LOADW(x, 31);
    COMPUTE(w, 30);
    COMPUTE(x, 31);
    __syncthreads(); // all fsmv reads done before act overwrite

    // BN (eval) + ReLU — identical formulas/order to rounds 1-6
    #pragma unroll
    for (int ci = 0; ci < 8; ++ci) {
        const int c = c0 + ci;
        const float inv = bng[c] / sqrtf(bnv[c] + BNEPS);
        const float mu = bnm[c];
        const float be = bnb[c];
        const float bb = b1[c];
        #pragma unroll
        for (int ri = 0; ri < 4; ++ri) {
            const float h = (acc[ri][ci] + bb - mu) * inv + be;
            acc[ri][ci] = fmaxf(h, 0.f);
        }
    }
    // act[r][c], stride 129 (2-way bank aliasing = free)
    #pragma unroll
    for (int ri = 0; ri < 4; ++ri)
        #pragma unroll
        for (int ci = 0; ci < 8; ++ci)
            smem[(r0 + ri) * 129 + c0 + ci] = acc[ri][ci];
    __syncthreads();

    // GEMM2: logits[r][o] = sum_c act[r][c] * W2[c][o]; sequential c order.
    const int r = tid & 63;
    const int ogrp = tid >> 6;  // wave-uniform
    float lg[3] = {0.f, 0.f, 0.f};
    for (int c = 0; c < 128; ++c) {
        const float a = smem[r * 129 + c];
        #pragma unroll
        for (int i = 0; i < 3; ++i) {
            const int o = ogrp + 4 * i;
            if (o < NCLS) lg[i] = fmaf(a, w2s[c * NCLS + o], lg[i]);
        }
    }
    const int n = gbase + r;
    const int b = n >> 15;          // NV = 2^15
    const int v = n & (NV - 1);
    unsigned int* sb = scoreb + (size_t)b * NK;
    #pragma unroll
    for (int i = 0; i < 3; ++i) {
        const int o = ogrp + 4 * i;
        if (o < NCLS) {
            const float x = lg[i] + b2s[o];
            const float s = 1.f / (1.f + expf(-x));
            const unsigned int u = __float_as_uint(s);
            sb[o * NV + v] = u;
            const int rel = (int)(u >> 16) - H1CUT;
            if (rel >= 0) atomicAdd(&lhist[rel], 1u); // max rel = 383 (s < 1.0)
        }
    }
    __syncthreads();
    for (int i = tid; i < H1BINS; i += 256)
        hist1p[(size_t)blockIdx.x * H1BINS + i] = lhist[i];
}

// ---------------------------------------------------------------------------
// B5: fused t1-compute + wide filter. grid (BCHUNKS, B), 384 threads.
// ---------------------------------------------------------------------------
__global__ __launch_bounds__(384) void stageB5_kernel(
    const unsigned int* __restrict__ scoreb,
    const unsigned int* __restrict__ hist1p,
    unsigned int* __restrict__ cnt, unsigned long long* __restrict__ cand)
{
    __shared__ unsigned int histS[H1BINS];
    __shared__ unsigned int s_t1;
    const int b = blockIdx.y;
    const int tid = threadIdx.x;

    {   // sum this batch's partial hists (coalesced across tid per j)
        unsigned int sum = 0;
        const unsigned int* hp = hist1p + (size_t)b * ABLKPERB * H1BINS + tid;
        #pragma unroll 8
        for (int j = 0; j < ABLKPERB; ++j) sum += hp[(size_t)j * H1BINS];
        histS[tid] = sum;
    }
    __syncthreads();
    if (tid == 0) {
        int above = 0;
        int c = H1BINS - 1;
        for (; c > 0; --c) {
            if (above + (int)histS[c] >= KSEL) break;
            above += (int)histS[c];
        }
        s_t1 = (unsigned int)(c + H1CUT);
    }
    __syncthreads();
    const unsigned int t1 = s_t1;

    const int base = blockIdx.x * CHUNKSZ;
    const unsigned int* sb = scoreb + (size_t)b * NK + base;
    for (int i = tid; i < CHUNKSZ; i += 384) {
        const unsigned int s = sb[i];
        if ((s >> 16) >= t1) {
            const unsigned int p = atomicAdd(&cnt[b], 1u);
            if (p < CANDCAP)
                cand[(size_t)b * CANDCAP + p] =
                    ((unsigned long long)s << 32) |
                    (unsigned long long)(0xFFFFFFFFu - (unsigned int)(base + i));
        }
    }
}

// ---------------------------------------------------------------------------
// B6: per batch exact rank-by-count selection (keys unique -> ranks unique).
// Exact hist2 fallback if candidate list overflowed (statistically never).
// ---------------------------------------------------------------------------
__global__ __launch_bounds__(1024) void stageB6_kernel(
    const unsigned int* __restrict__ scoreb,
    const unsigned int* __restrict__ hist1p,
    const unsigned int* __restrict__ cntg,
    const unsigned long long* __restrict__ candg,
    unsigned int* __restrict__ hist2,
    float* __restrict__ sel_score, int* __restrict__ sel_cls, int* __restrict__ sel_vox)
{
    __shared__ unsigned long long candL[CANDCAP];
    __shared__ unsigned int csum[1024];
    __shared__ unsigned int histS[H1BINS];
    __shared__ int s_cnt;
    __shared__ unsigned int s_T;
    const int b = blockIdx.x;
    const int tid = threadIdx.x;
    const unsigned int* sb = scoreb + (size_t)b * NK;
    int cnt = (int)cntg[b];

    if (cnt <= CANDCAP) {
        for (int i = tid; i < cnt; i += 1024)
            candL[i] = candg[(size_t)b * CANDCAP + i];
        __syncthreads();
    } else {
        // fallback: recompute t1/g1, refine exact 32-bit threshold via hist2
        if (tid < H1BINS) {
            unsigned int sum = 0;
            const unsigned int* hp = hist1p + (size_t)b * ABLKPERB * H1BINS + tid;
            for (int j = 0; j < ABLKPERB; ++j) sum += hp[(size_t)j * H1BINS];
            histS[tid] = sum;
        }
        __syncthreads();
        if (tid == 0) {
            int above = 0;
            int c = H1BINS - 1;
            for (; c > 0; --c) {
                if (above + (int)histS[c] >= KSEL) break;
                above += (int)histS[c];
            }
            s_T = (unsigned int)(c + H1CUT);   // temp: t1
            s_cnt = above;                      // temp: g1
        }
        __syncthreads();
        const unsigned int t1 = s_T;
        const unsigned int g1 = (unsigned int)s_cnt;
        __syncthreads();
        for (int i = tid; i < NK; i += 1024) {
            const unsigned int s = sb[i];
            if ((s >> 16) == t1) atomicAdd(&hist2[(size_t)b * 65536 + (s & 0xFFFFu)], 1u);
        }
        __threadfence();
        __syncthreads();
        {
            const uint4* h4 = (const uint4*)(hist2 + (size_t)b * 65536 + tid * 64);
            unsigned int sum = 0;
            #pragma unroll
            for (int i = 0; i < 16; ++i) { const uint4 v = h4[i]; sum += v.x + v.y + v.z + v.w; }
            csum[tid] = sum;
        }
        __syncthreads();
        if (tid == 0) {
            const int need = KSEL - (int)g1;
            int above = 0;
            int c = 1023;
            for (; c > 0; --c) {
                if (above + (int)csum[c] >= need) break;
                above += (int)csum[c];
            }
            const unsigned int* h2 = hist2 + (size_t)b * 65536 + c * 64;
            const int need2 = need - above;
            int above2 = 0;
            int j = 63;
            for (; j > 0; --j) {
                if (above2 + (int)h2[j] >= need2) break;
                above2 += (int)h2[j];
            }
            s_T = (t1 << 16) | (unsigned int)(c * 64 + j);
            s_cnt = 0;
        }
        __syncthreads();
        const unsigned int T = s_T;
        for (int i = tid; i < NK; i += 1024) {
            const unsigned int s = sb[i];
            if (s >= T) {
                const int p = atomicAdd(&s_cnt, 1);
                if (p < CANDCAP)
                    candL[p] = ((unsigned long long)s << 32) |
                               (unsigned long long)(0xFFFFFFFFu - (unsigned int)i);
            }
        }
        __syncthreads();
        cnt = min(s_cnt, CANDCAP);
        __syncthreads();
    }

    // exact selection by rank (order-independent, deterministic)
    for (int i = tid; i < cnt; i += 1024) {
        const unsigned long long key = candL[i];
        int rank = 0;
        for (int j = 0; j < cnt; ++j)
            rank += (candL[j] > key) ? 1 : 0;     // LDS broadcast reads
        if (rank < KSEL) {
            const unsigned int s32 = (unsigned int)(key >> 32);
            const unsigned int fl = 0xFFFFFFFFu - (unsigned int)(key & 0xFFFFFFFFull);
            const int idx = b * KSEL + rank;
            sel_score[idx] = __uint_as_float(s32);
            sel_cls[idx] = (int)(fl >> 15);
            sel_vox[idx] = (int)(fl & (NV - 1));
        }
    }
}

// ---------------------------------------------------------------------------
// Stage C: heads 1..5 for selected voxels. grid = (total/8, 5); 128 thr.
// ---------------------------------------------------------------------------
__global__ __launch_bounds__(128) void stageC_kernel(
    const float* __restrict__ feats,
    const int* __restrict__ sel_vox,
    const float* __restrict__ W1,
    const float* __restrict__ b1,
    const float* __restrict__ bng,
    const float* __restrict__ bnb,
    const float* __restrict__ bnm,
    const float* __restrict__ bnv,
    const float* __restrict__ W2c, const float* __restrict__ b2c,
    const float* __restrict__ W2z, const float* __restrict__ b2z,
    const float* __restrict__ W2d, const float* __restrict__ b2d,
    const float* __restrict__ W2r, const float* __restrict__ b2r,
    const float* __restrict__ W2v, const float* __restrict__ b2v,
    float* __restrict__ dec)
{
    __shared__ float fs[8][128];
    __shared__ float as_[8][128];
    __shared__ int vsel[8];
    const int tid = threadIdx.x;
    const int head = blockIdx.y + 1;
    const int s0 = blockIdx.x * 8;

    if (tid < 8) {
        const int s = s0 + tid;
        vsel[tid] = (s / KSEL) * NV + sel_vox[s];
    }
    __syncthreads();
    for (int t = tid; t < 8 * 128; t += 128) {
        const int j = t >> 7;
        const int c = t & 127;
        fs[j][c] = feats[((size_t)vsel[j] << 7) + c];
    }
    __syncthreads();

    const int c = tid;
    float acc[8];
    #pragma unroll
    for (int j = 0; j < 8; ++j) acc[j] = 0.f;
    const float* Wh = W1 + head * (CD * CD);
    #pragma unroll 4
    for (int k = 0; k < 128; ++k) {
        const float w = Wh[(k << 7) + c];
        #pragma unroll
        for (int j = 0; j < 8; ++j) acc[j] = fmaf(fs[j][k], w, acc[j]);
    }
    const int hc = head * CD + c;
    const float inv = bng[hc] / sqrtf(bnv[hc] + BNEPS);
    const float mu = bnm[hc], be = bnb[hc], bb = b1[hc];
    #pragma unroll
    for (int j = 0; j < 8; ++j) {
        const float h = (acc[j] + bb - mu) * inv + be;
        as_[j][c] = fmaxf(h, 0.f);
    }
    __syncthreads();

    const float* w2; const float* bb2; int oc, off; bool ex = false;
    if (head == 1)      { w2 = W2c; bb2 = b2c; oc = 2; off = 0; }
    else if (head == 2) { w2 = W2z; bb2 = b2z; oc = 1; off = 2; }
    else if (head == 3) { w2 = W2d; bb2 = b2d; oc = 3; off = 3; ex = true; }
    else if (head == 4) { w2 = W2r; bb2 = b2r; oc = 2; off = 6; }
    else                { w2 = W2v; bb2 = b2v; oc = 2; off = 8; }

    for (int t = tid; t < 8 * oc; t += 128) {
        const int j = t / oc;
        const int o = t % oc;
        float a = 0.f;
        for (int cc = 0; cc < 128; ++cc) a = fmaf(as_[j][cc], w2[cc * oc + o], a);
        a += bb2[o];
        if (ex) a = expf(a);
        dec[(size_t)(s0 + j) * 10 + off + o] = a;
    }
}

// ---------------------------------------------------------------------------
// Stage D: decode boxes + mask, write outputs.
// ---------------------------------------------------------------------------
__global__ void stageD_kernel(
    const int* __restrict__ voxel_xy,
    const float* __restrict__ sel_score,
    const int* __restrict__ sel_cls,
    const int* __restrict__ sel_vox,
    const float* __restrict__ dec,
    float* __restrict__ out,
    int total)
{
    const int s = blockIdx.x * blockDim.x + threadIdx.x;
    if (s >= total) return;
    const int b = s / KSEL;
    const float score = sel_score[s];
    const int cls = sel_cls[s];
    const int v = sel_vox[s];
    const int n = b * NV + v;
    const float xi = (float)voxel_xy[2 * n];
    const float yi = (float)voxel_xy[2 * n + 1];
    const float* dd = dec + (size_t)s * 10;
    const float cx = dd[0], cy = dd[1], cz = dd[2];
    const float d0 = dd[3], d1 = dd[4], d2 = dd[5];
    const float rc = dd[6], rs = dd[7], ve0 = dd[8], ve1 = dd[9];
    const float SV = 0.075f * 8.0f;
    const float xs = (xi + cx) * SV + (-54.0f);
    const float ys = (yi + cy) * SV + (-54.0f);
    const float ang = atan2f(rs, rc);
    const bool mk = (xs >= -61.2f) && (ys >= -61.2f) && (cz >= -10.0f) &&
                    (xs <= 61.2f) && (ys <= 61.2f) && (cz <= 10.0f) &&
                    (score > 0.1f);
    const float m = mk ? 1.f : 0.f;
    float* bx = out + (size_t)s * 10;
    bx[0] = xs * m; bx[1] = ys * m; bx[2] = cz * m;
    bx[3] = d0 * m; bx[4] = d1 * m; bx[5] = d2 * m;
    bx[6] = ang * m; bx[7] = ve0 * m; bx[8] = ve1 * m; bx[9] = score * m;
    out[(size_t)total * 10 + s] = mk ? (float)(cls + 1) : 0.f;
    out[(size_t)total * 11 + s] = (float)n;
    out[(size_t)total * 12 + s] = m;
}

extern "C" void kernel_launch(void* const* d_in, const int* in_sizes, int n_in,
                              void* d_out, int out_size, void* d_ws, size_t ws_size,
                              hipStream_t stream) {
    const float* feats   = (const float*)d_in[0];
    const int*   voxelxy = (const int*)d_in[1];
    const float* W1   = (const float*)d_in[2];
    const float* b1   = (const float*)d_in[3];
    const float* bng  = (const float*)d_in[4];
    const float* bnb  = (const float*)d_in[5];
    const float* bnm  = (const float*)d_in[6];
    const float* bnv  = (const float*)d_in[7];
    const float* W2hm = (const float*)d_in[8];
    const float* b2hm = (const float*)d_in[9];
    const float* W2c  = (const float*)d_in[10];
    const float* b2c  = (const float*)d_in[11];
    const float* W2z  = (const float*)d_in[12];
    const float* b2z  = (const float*)d_in[13];
    const float* W2d  = (const float*)d_in[14];
    const float* b2d  = (const float*)d_in[15];
    const float* W2r  = (const float*)d_in[16];
    const float* b2r  = (const float*)d_in[17];
    const float* W2v  = (const float*)d_in[18];
    const float* b2v  = (const float*)d_in[19];

    const int B = in_sizes[0] / (NV * CD);
    const int N = B * NV;
    const int total = B * KSEL;
    const int nblkA = N / ABLKROWS;

    // workspace layout (8-byte aligned chunks)
    char* ws = (char*)d_ws;
    unsigned int* scoreb = (unsigned int*)ws;   ws += (size_t)B * NK * 4;
    unsigned int* hist1p = (unsigned int*)ws;   ws += (size_t)nblkA * H1BINS * 4;
    unsigned int* hist2  = (unsigned int*)ws;   ws += (size_t)B * 65536 * 4;
    unsigned long long* cand = (unsigned long long*)ws; ws += (size_t)B * CANDCAP * 8;
    unsigned int* cnt    = (unsigned int*)ws;   ws += 8 * 4;
    float* sel_score = (float*)ws;              ws += (size_t)total * 4;
    int*   sel_cls   = (int*)ws;                ws += (size_t)total * 4;
    int*   sel_vox   = (int*)ws;                ws += (size_t)total * 4;
    float* dec       = (float*)ws;              ws += (size_t)total * 10 * 4;

    stageA_kernel<<<dim3(nblkA), dim3(256), 0, stream>>>(
        feats, W1, b1, bng, bnb, bnm, bnv, W2hm, b2hm, scoreb, hist1p, hist2, cnt);

    stageB5_kernel<<<dim3(BCHUNKS, B), dim3(384), 0, stream>>>(
        scoreb, hist1p, cnt, cand);
    stageB6_kernel<<<dim3(B), dim3(1024), 0, stream>>>(
        scoreb, hist1p, cnt, cand, hist2, sel_score, sel_cls, sel_vox);

    stageC_kernel<<<dim3(total / 8, 5), dim3(128), 0, stream>>>(
        feats, sel_vox, W1, b1, bng, bnb, bnm, bnv,
        W2c, b2c, W2z, b2z, W2d, b2d, W2r, b2r, W2v, b2v, dec);
    stageD_kernel<<<dim3((total + 255) / 256), dim3(256), 0, stream>>>(
        voxelxy, sel_score, sel_cls, sel_vox, dec, (float*)d_out, total);
}